// Round 1
// baseline (290.621 us; speedup 1.0000x reference)
//
#include <hip/hip_runtime.h>

// out[e, i, c] = sum_j inv[e, i, j] * conv[mesh[e, j], c]
// E = 2,000,000 elements, K = 4, C = 3.
// Memory-bound: ~261 MB HBM traffic (conv gather is L2/L3-resident, 4.8 MB).

__global__ __launch_bounds__(256) void
elem_matmul_kernel(const float* __restrict__ conv,
                   const int* __restrict__ mesh,
                   const float* __restrict__ inv,
                   float* __restrict__ out,
                   int E) {
    int e = blockIdx.x * blockDim.x + threadIdx.x;
    if (e >= E) return;

    // Coalesced 16 B index load
    const int4 idx = *reinterpret_cast<const int4*>(mesh + 4 * (size_t)e);

    // Coalesced-ish 64 B inverse-matrix load (4x float4 per lane)
    const float4* ip = reinterpret_cast<const float4*>(inv + 16 * (size_t)e);
    const float4 r0 = ip[0];
    const float4 r1 = ip[1];
    const float4 r2 = ip[2];
    const float4 r3 = ip[3];

    // Gather 4 vertex convection vectors (3 floats each) — L2-resident
    const int vs[4] = {idx.x, idx.y, idx.z, idx.w};
    float g[4][3];
#pragma unroll
    for (int j = 0; j < 4; ++j) {
        const float* p = conv + 3 * (size_t)vs[j];
        g[j][0] = p[0];
        g[j][1] = p[1];
        g[j][2] = p[2];
    }

    // o[i][c] = inv_row_i . g[:, c]  (48 FMAs)
    float o[4][3];
#pragma unroll
    for (int c = 0; c < 3; ++c) {
        o[0][c] = r0.x * g[0][c] + r0.y * g[1][c] + r0.z * g[2][c] + r0.w * g[3][c];
        o[1][c] = r1.x * g[0][c] + r1.y * g[1][c] + r1.z * g[2][c] + r1.w * g[3][c];
        o[2][c] = r2.x * g[0][c] + r2.y * g[1][c] + r2.z * g[2][c] + r2.w * g[3][c];
        o[3][c] = r3.x * g[0][c] + r3.y * g[1][c] + r3.z * g[2][c] + r3.w * g[3][c];
    }

    // 48 B contiguous store per element; base offset 48*e is 16-B aligned
    float4* op = reinterpret_cast<float4*>(out + 12 * (size_t)e);
    op[0] = make_float4(o[0][0], o[0][1], o[0][2], o[1][0]);
    op[1] = make_float4(o[1][1], o[1][2], o[2][0], o[2][1]);
    op[2] = make_float4(o[2][2], o[3][0], o[3][1], o[3][2]);
}

extern "C" void kernel_launch(void* const* d_in, const int* in_sizes, int n_in,
                              void* d_out, int out_size, void* d_ws, size_t ws_size,
                              hipStream_t stream) {
    const float* conv = (const float*)d_in[0];   // (N_NODES, 3) f32
    const int* mesh = (const int*)d_in[1];       // (E, 4) i32
    const float* inv = (const float*)d_in[2];    // (E, 4, 4) f32
    float* out = (float*)d_out;                  // (E, 4, 3) f32

    const int E = in_sizes[1] / 4;
    const int block = 256;
    const int grid = (E + block - 1) / block;
    elem_matmul_kernel<<<grid, block, 0, stream>>>(conv, mesh, inv, out, E);
}